// Round 4
// baseline (106.777 us; speedup 1.0000x reference)
//
#include <hip/hip_runtime.h>
#include <hip/hip_bf16.h>

// GaussianKernel: S[i][j] = exp(-||H1_i - H2_j||^2), N=8192, K=64, fp32 out.
// Round 4: prep kernel converts fp32 -> LINEAR bf16 hi/lo planes + norms in
// d_ws (once, 4 MiB). Main kernel has NO LDS, NO barrier, NO conversion:
// MFMA fragments load directly from the L2-resident planes. Split-bf16
// (3 mfma passes) for fp32-grade accuracy. Regular float4 stores.

typedef float  f32x4  __attribute__((ext_vector_type(4)));
typedef short  short8 __attribute__((ext_vector_type(8)));
typedef unsigned short ushort8 __attribute__((ext_vector_type(8)));

#define KD 64

#define PLANE  (1u << 20)                 // 1 MiB per bf16 plane (8192*64*2B)
#define OFF_N1 (4u * PLANE)
#define OFF_N2 (4u * PLANE + 8192u * 4u)
#define WS_NEED ((size_t)(4u * PLANE + 2u * 8192u * 4u))

__device__ __forceinline__ unsigned short f2bf(float x) {
    __hip_bfloat16 h = __float2bfloat16(x);   // RNE
    unsigned short u;
    __builtin_memcpy(&u, &h, 2);
    return u;
}
__device__ __forceinline__ float bf2f(unsigned short u) {
    unsigned int v = ((unsigned int)u) << 16;
    float f;
    __builtin_memcpy(&f, &v, 4);
    return f;
}

// ---------------- prep: fp32 -> linear bf16 hi/lo planes + row norms ----------------
__global__ __launch_bounds__(256) void gauss_prep(const float* __restrict__ H1,
                                                  const float* __restrict__ H2,
                                                  unsigned char* __restrict__ ws)
{
    const int cid   = blockIdx.x * 256 + threadIdx.x;   // 0..131071
    const int which = cid >> 16;                        // 0:H1 1:H2
    const int g     = cid & 65535;                      // 16B-chunk id in input
    const int row   = g >> 3;
    const int kc    = g & 7;

    const float* src = which ? H2 : H1;
    const f32x4* p = (const f32x4*)(src + (size_t)g * 8);
    f32x4 v0 = p[0], v1 = p[1];

    ushort8 h, l;
    float s = 0.f;
    #pragma unroll
    for (int e = 0; e < 8; ++e) {
        float a = (e < 4) ? v0[e] : v1[e - 4];
        unsigned short hb = f2bf(a);
        h[e] = hb;
        l[e] = f2bf(a - bf2f(hb));
        s = fmaf(a, a, s);
    }
    s += __shfl_xor(s, 1);
    s += __shfl_xor(s, 2);
    s += __shfl_xor(s, 4);

    unsigned char* hi = ws + (which ? 2u * PLANE : 0u) + (size_t)g * 16u;
    unsigned char* lo = hi + PLANE;
    *(ushort8*)hi = h;
    *(ushort8*)lo = l;
    if (kc == 0)
        *(float*)(ws + (which ? OFF_N2 : OFF_N1) + (size_t)row * 4u) = s;
}

// ---------------- main: no LDS, fragments straight from L2 ----------------
__global__ __launch_bounds__(256, 3) void gauss_main(
    const unsigned char* __restrict__ ws, float* __restrict__ out, int N2)
{
    const int t    = threadIdx.x;
    const int lane = t & 63, w = t >> 6;     // 4 waves
    const int wr = w >> 1, wc = w & 1;       // 2x2 wave grid, 64x64 each
    const int lr = lane & 15;                // output-row index in fragment
    const int kb = lane >> 4;                // k-block / col-group
    const int r4 = kb * 4;
    const int row0 = blockIdx.y * 128;
    const int col0 = blockIdx.x * 128;

    const unsigned char* hi1 = ws;
    const unsigned char* lo1 = ws + PLANE;
    const unsigned char* hi2 = ws + 2u * PLANE;
    const unsigned char* lo2 = ws + 3u * PLANE;
    const float* nrm1 = (const float*)(ws + OFF_N1);
    const float* nrm2 = (const float*)(ws + OFF_N2);

    float n1v[4];
    f32x4 n2v[4];
    #pragma unroll
    for (int fr = 0; fr < 4; ++fr)
        n1v[fr] = nrm1[row0 + wr * 64 + fr * 16 + lr];
    #pragma unroll
    for (int fc = 0; fc < 4; ++fc)
        n2v[fc] = *(const f32x4*)(nrm2 + col0 + wc * 64 + fc * 16 + r4);

    f32x4 acc[4][4];
    #pragma unroll
    for (int a = 0; a < 4; ++a)
        #pragma unroll
        for (int b = 0; b < 4; ++b)
            acc[a][b] = (f32x4){0.f, 0.f, 0.f, 0.f};

    #pragma unroll
    for (int ks = 0; ks < 2; ++ks) {
        const unsigned kByte = (unsigned)(ks * 64 + kb * 16);
        short8 ah[4], al[4];
        #pragma unroll
        for (int fr = 0; fr < 4; ++fr) {
            size_t off = (size_t)(row0 + wr * 64 + fr * 16 + lr) * 128u + kByte;
            ah[fr] = *(const short8*)(hi1 + off);
            al[fr] = *(const short8*)(lo1 + off);
        }
        #pragma unroll
        for (int fc = 0; fc < 4; ++fc) {
            size_t off = (size_t)(col0 + wc * 64 + fc * 16 + lr) * 128u + kByte;
            short8 bh = *(const short8*)(hi2 + off);
            short8 bl = *(const short8*)(lo2 + off);
            #pragma unroll
            for (int fr = 0; fr < 4; ++fr) {
                // swapped operands (verified R2/R3): D's j-dim walks output
                // COLUMNS (H2 rows), D's lane&15 dim walks output ROWS.
                acc[fr][fc] = __builtin_amdgcn_mfma_f32_16x16x32_bf16(bh, ah[fr], acc[fr][fc], 0, 0, 0);
                acc[fr][fc] = __builtin_amdgcn_mfma_f32_16x16x32_bf16(bl, ah[fr], acc[fr][fc], 0, 0, 0);
                acc[fr][fc] = __builtin_amdgcn_mfma_f32_16x16x32_bf16(bh, al[fr], acc[fr][fc], 0, 0, 0);
            }
        }
    }

    // epilogue: out = exp(-(n1 + n2 - 2*dot)), float4 regular stores
    #pragma unroll
    for (int fr = 0; fr < 4; ++fr) {
        const int grow = row0 + wr * 64 + fr * 16 + lr;
        float* orow = out + (size_t)grow * (size_t)N2 + (col0 + wc * 64 + r4);
        #pragma unroll
        for (int fc = 0; fc < 4; ++fc) {
            f32x4 cst;
            #pragma unroll
            for (int j = 0; j < 4; ++j) {
                float d2 = fmaf(-2.0f, acc[fr][fc][j], n1v[fr] + n2v[fc][j]);
                cst[j] = __expf(-d2);
            }
            *(f32x4*)(orow + fc * 16) = cst;
        }
    }
}

// ---------------- fallback (R3 kernel): in-kernel conversion via LDS ----------------
__device__ __forceinline__ unsigned panel_off(unsigned row, unsigned kcByte) {
    return (row * 128u + kcByte) ^ ((row & 7u) << 4);
}

__global__ __launch_bounds__(512, 4) void gauss_fallback(
    const float* __restrict__ H1, const float* __restrict__ H2,
    float* __restrict__ out, int N2)
{
    __shared__ __align__(16) unsigned char sAhi[128 * 128];
    __shared__ __align__(16) unsigned char sAlo[128 * 128];
    __shared__ __align__(16) unsigned char sBhi[128 * 128];
    __shared__ __align__(16) unsigned char sBlo[128 * 128];
    __shared__ __align__(16) float snrm[256];

    const int t    = threadIdx.x;
    const int lane = t & 63, w = t >> 6;
    const int wr = w >> 2, wc = w & 3;
    const int lr = lane & 15, kb = lane >> 4, r4 = kb * 4;
    const int row0 = blockIdx.y * 128, col0 = blockIdx.x * 128;

    #pragma unroll
    for (int side = 0; side < 2; ++side) {
        const float* src = side ? (H2 + (size_t)col0 * KD) : (H1 + (size_t)row0 * KD);
        unsigned char* hi = side ? sBhi : sAhi;
        unsigned char* lo = side ? sBlo : sAlo;
        #pragma unroll
        for (int i = 0; i < 2; ++i) {
            int g = i * 512 + t, row = g >> 3, kc = g & 7;
            const f32x4* p = (const f32x4*)(src + (size_t)g * 8);
            f32x4 v0 = p[0], v1 = p[1];
            ushort8 h, l;
            float s = 0.f;
            #pragma unroll
            for (int e = 0; e < 8; ++e) {
                float a = (e < 4) ? v0[e] : v1[e - 4];
                unsigned short hb = f2bf(a);
                h[e] = hb;
                l[e] = f2bf(a - bf2f(hb));
                s = fmaf(a, a, s);
            }
            s += __shfl_xor(s, 1);
            s += __shfl_xor(s, 2);
            s += __shfl_xor(s, 4);
            unsigned off = panel_off((unsigned)row, (unsigned)kc * 16u);
            *(ushort8*)(hi + off) = h;
            *(ushort8*)(lo + off) = l;
            if (kc == 0) snrm[side * 128 + row] = s;
        }
    }
    __syncthreads();

    float n1v[4];
    f32x4 n2v[2];
    #pragma unroll
    for (int fr = 0; fr < 4; ++fr) n1v[fr] = snrm[wr * 64 + fr * 16 + lr];
    #pragma unroll
    for (int fc = 0; fc < 2; ++fc) n2v[fc] = *(const f32x4*)&snrm[128 + wc * 32 + fc * 16 + r4];

    f32x4 acc[4][2];
    #pragma unroll
    for (int a = 0; a < 4; ++a)
        #pragma unroll
        for (int b = 0; b < 2; ++b)
            acc[a][b] = (f32x4){0.f, 0.f, 0.f, 0.f};

    #pragma unroll
    for (int ks = 0; ks < 2; ++ks) {
        const unsigned kByte = (unsigned)(ks * 64 + kb * 16);
        short8 ah[4], al[4];
        #pragma unroll
        for (int fr = 0; fr < 4; ++fr) {
            const unsigned off = panel_off((unsigned)(wr * 64 + fr * 16 + lr), kByte);
            ah[fr] = *(const short8*)(sAhi + off);
            al[fr] = *(const short8*)(sAlo + off);
        }
        #pragma unroll
        for (int fc = 0; fc < 2; ++fc) {
            const unsigned off = panel_off((unsigned)(wc * 32 + fc * 16 + lr), kByte);
            short8 bh = *(const short8*)(sBhi + off);
            short8 bl = *(const short8*)(sBlo + off);
            #pragma unroll
            for (int fr = 0; fr < 4; ++fr) {
                acc[fr][fc] = __builtin_amdgcn_mfma_f32_16x16x32_bf16(bh, ah[fr], acc[fr][fc], 0, 0, 0);
                acc[fr][fc] = __builtin_amdgcn_mfma_f32_16x16x32_bf16(bl, ah[fr], acc[fr][fc], 0, 0, 0);
                acc[fr][fc] = __builtin_amdgcn_mfma_f32_16x16x32_bf16(bh, al[fr], acc[fr][fc], 0, 0, 0);
            }
        }
    }

    #pragma unroll
    for (int fr = 0; fr < 4; ++fr) {
        const int grow = row0 + wr * 64 + fr * 16 + lr;
        float* orow = out + (size_t)grow * (size_t)N2 + (col0 + wc * 32 + r4);
        #pragma unroll
        for (int fc = 0; fc < 2; ++fc) {
            f32x4 cst;
            #pragma unroll
            for (int j = 0; j < 4; ++j) {
                float d2 = fmaf(-2.0f, acc[fr][fc][j], n1v[fr] + n2v[fc][j]);
                cst[j] = __expf(-d2);
            }
            *(f32x4*)(orow + fc * 16) = cst;
        }
    }
}

extern "C" void kernel_launch(void* const* d_in, const int* in_sizes, int n_in,
                              void* d_out, int out_size, void* d_ws, size_t ws_size,
                              hipStream_t stream) {
    const float* H1 = (const float*)d_in[0];
    const float* H2 = (const float*)d_in[1];
    float* out = (float*)d_out;
    const int n1 = in_sizes[0] / KD;   // 8192
    const int n2 = in_sizes[1] / KD;   // 8192
    dim3 grid(n2 / 128, n1 / 128);

    if (ws_size >= WS_NEED) {
        gauss_prep<<<dim3(512), dim3(256), 0, stream>>>(H1, H2, (unsigned char*)d_ws);
        gauss_main<<<grid, dim3(256), 0, stream>>>((const unsigned char*)d_ws, out, n2);
    } else {
        gauss_fallback<<<grid, dim3(512), 0, stream>>>(H1, H2, out, n2);
    }
}

// Round 5
// 65.629 us; speedup vs baseline: 1.6270x; 1.6270x over previous
//
#include <hip/hip_runtime.h>
#include <hip/hip_bf16.h>

// GaussianKernel: S[i][j] = exp(-||H1_i - H2_j||^2), N=8192, K=64, fp32 out.
// Round 5: prep (verified R4) converts fp32 -> LINEAR bf16 hi/lo planes +
// norms once. Main: 64x64 tiles, 32 KiB LDS (4 blocks/CU), XOR-swizzled
// staging from pre-converted planes (coalesced 16B loads), swapped-operand
// MFMA -> float4 stores (verified). Fallback = exact R1 champion kernel.

typedef float  f32x4  __attribute__((ext_vector_type(4)));
typedef short  short8 __attribute__((ext_vector_type(8)));
typedef unsigned short ushort8 __attribute__((ext_vector_type(8)));

#define KD 64

#define PLANE  (1u << 20)                 // 1 MiB per bf16 plane (8192*64*2B)
#define OFF_N1 (4u * PLANE)
#define OFF_N2 (4u * PLANE + 8192u * 4u)
#define WS_NEED ((size_t)(4u * PLANE + 2u * 8192u * 4u))

__device__ __forceinline__ unsigned short f2bf(float x) {
    __hip_bfloat16 h = __float2bfloat16(x);   // RNE
    unsigned short u;
    __builtin_memcpy(&u, &h, 2);
    return u;
}
__device__ __forceinline__ float bf2f(unsigned short u) {
    unsigned int v = ((unsigned int)u) << 16;
    float f;
    __builtin_memcpy(&f, &v, 4);
    return f;
}

// swizzled byte offset of (row, 16B-chunk byte) in a [rows][64]-bf16 panel
__device__ __forceinline__ unsigned panel_off(unsigned row, unsigned kcByte) {
    return (row * 128u + kcByte) ^ ((row & 7u) << 4);
}

// ---------------- prep: fp32 -> linear bf16 hi/lo planes + row norms ----------------
// (verified bit-exact in R2/R4)
__global__ __launch_bounds__(256) void gauss_prep(const float* __restrict__ H1,
                                                  const float* __restrict__ H2,
                                                  unsigned char* __restrict__ ws)
{
    const int cid   = blockIdx.x * 256 + threadIdx.x;   // 0..131071
    const int which = cid >> 16;                        // 0:H1 1:H2
    const int g     = cid & 65535;                      // 16B-chunk id in input
    const int row   = g >> 3;
    const int kc    = g & 7;

    const float* src = which ? H2 : H1;
    const f32x4* p = (const f32x4*)(src + (size_t)g * 8);
    f32x4 v0 = p[0], v1 = p[1];

    ushort8 h, l;
    float s = 0.f;
    #pragma unroll
    for (int e = 0; e < 8; ++e) {
        float a = (e < 4) ? v0[e] : v1[e - 4];
        unsigned short hb = f2bf(a);
        h[e] = hb;
        l[e] = f2bf(a - bf2f(hb));
        s = fmaf(a, a, s);
    }
    s += __shfl_xor(s, 1);
    s += __shfl_xor(s, 2);
    s += __shfl_xor(s, 4);

    unsigned char* hi = ws + (which ? 2u * PLANE : 0u) + (size_t)g * 16u;
    unsigned char* lo = hi + PLANE;
    *(ushort8*)hi = h;
    *(ushort8*)lo = l;
    if (kc == 0)
        *(float*)(ws + (which ? OFF_N2 : OFF_N1) + (size_t)row * 4u) = s;
}

// ---------------- main: 64x64 tile, LDS-staged from planes ----------------
__global__ __launch_bounds__(256, 4) void gauss_main(
    const unsigned char* __restrict__ ws, float* __restrict__ out, int N2)
{
    // 4 panels of 8 KiB: Ahi | Alo | Bhi | Blo
    __shared__ __align__(16) unsigned char smem[4][8192];

    const int t    = threadIdx.x;
    const int lane = t & 63, w = t >> 6;     // 4 waves
    const int wr = w >> 1, wc = w & 1;       // 2x2 wave grid, 32x32 each
    const int lr = lane & 15;
    const int kb = lane >> 4;
    const int r4 = kb * 4;
    const int row0 = blockIdx.y * 64;
    const int col0 = blockIdx.x * 64;

    const float* nrm1 = (const float*)(ws + OFF_N1);
    const float* nrm2 = (const float*)(ws + OFF_N2);

    // ---- stage 4 panels: coalesced 16B loads, swizzled ds_write ----
    #pragma unroll
    for (int p = 0; p < 4; ++p) {
        const int panel0 = (p < 2) ? row0 : col0;
        const unsigned char* plane = ws + (size_t)p * PLANE;
        #pragma unroll
        for (int i = 0; i < 2; ++i) {
            int idx = i * 256 + t;              // 16B chunk 0..511
            int row = idx >> 3;                 // 0..63
            int kc  = idx & 7;
            ushort8 v = *(const ushort8*)(plane + (size_t)(panel0 + row) * 128u
                                                + (size_t)kc * 16u);
            *(ushort8*)(smem[p] + panel_off((unsigned)row, (unsigned)kc * 16u)) = v;
        }
    }
    __syncthreads();

    // ---- norms into registers (pattern verified in R4) ----
    float n1v[2];
    f32x4 n2v[2];
    #pragma unroll
    for (int fr = 0; fr < 2; ++fr)
        n1v[fr] = nrm1[row0 + wr * 32 + fr * 16 + lr];
    #pragma unroll
    for (int fc = 0; fc < 2; ++fc)
        n2v[fc] = *(const f32x4*)(nrm2 + col0 + wc * 32 + fc * 16 + r4);

    // ---- MFMA: each wave owns 32x32, split-bf16 3-pass ----
    f32x4 acc[2][2];
    #pragma unroll
    for (int a = 0; a < 2; ++a)
        #pragma unroll
        for (int b = 0; b < 2; ++b)
            acc[a][b] = (f32x4){0.f, 0.f, 0.f, 0.f};

    #pragma unroll
    for (int ks = 0; ks < 2; ++ks) {
        const unsigned kByte = (unsigned)(ks * 64 + kb * 16);
        short8 ah[2], al[2];
        #pragma unroll
        for (int fr = 0; fr < 2; ++fr) {
            const unsigned off = panel_off((unsigned)(wr * 32 + fr * 16 + lr), kByte);
            ah[fr] = *(const short8*)(smem[0] + off);
            al[fr] = *(const short8*)(smem[1] + off);
        }
        #pragma unroll
        for (int fc = 0; fc < 2; ++fc) {
            const unsigned off = panel_off((unsigned)(wc * 32 + fc * 16 + lr), kByte);
            short8 bh = *(const short8*)(smem[2] + off);
            short8 bl = *(const short8*)(smem[3] + off);
            #pragma unroll
            for (int fr = 0; fr < 2; ++fr) {
                // swapped operands (verified): D's lane&15 dim -> output rows,
                // D's j dim -> output cols.
                acc[fr][fc] = __builtin_amdgcn_mfma_f32_16x16x32_bf16(bh, ah[fr], acc[fr][fc], 0, 0, 0);
                acc[fr][fc] = __builtin_amdgcn_mfma_f32_16x16x32_bf16(bl, ah[fr], acc[fr][fc], 0, 0, 0);
                acc[fr][fc] = __builtin_amdgcn_mfma_f32_16x16x32_bf16(bh, al[fr], acc[fr][fc], 0, 0, 0);
            }
        }
    }

    // ---- epilogue: out = exp(-(n1 + n2 - 2*dot)), float4 stores ----
    #pragma unroll
    for (int fr = 0; fr < 2; ++fr) {
        const int grow = row0 + wr * 32 + fr * 16 + lr;
        float* orow = out + (size_t)grow * (size_t)N2 + (col0 + wc * 32 + r4);
        #pragma unroll
        for (int fc = 0; fc < 2; ++fc) {
            f32x4 cst;
            #pragma unroll
            for (int j = 0; j < 4; ++j) {
                float d2 = fmaf(-2.0f, acc[fr][fc][j], n1v[fr] + n2v[fc][j]);
                cst[j] = __expf(-d2);
            }
            *(f32x4*)(orow + fc * 16) = cst;
        }
    }
}

// ---------------- fallback: exact R1 champion kernel ----------------
__global__ __launch_bounds__(256, 2) void gauss_fallback(
    const float* __restrict__ H1, const float* __restrict__ H2,
    float* __restrict__ out, int N1, int N2)
{
    __shared__ __align__(16) unsigned short sAhi[128 * KD];
    __shared__ __align__(16) unsigned short sAlo[128 * KD];
    __shared__ __align__(16) unsigned short sBhi[128 * KD];
    __shared__ __align__(16) unsigned short sBlo[128 * KD];
    __shared__ float snrm[256];

    const int t = threadIdx.x;
    const int row0 = blockIdx.y * 128;
    const int col0 = blockIdx.x * 128;

    #pragma unroll
    for (int side = 0; side < 2; ++side) {
        const float* src = side ? (H2 + (size_t)col0 * KD) : (H1 + (size_t)row0 * KD);
        unsigned short* hi = side ? sBhi : sAhi;
        unsigned short* lo = side ? sBlo : sAlo;
        #pragma unroll
        for (int i = 0; i < 4; ++i) {
            int g = i * 256 + t, row = g >> 3, kc = g & 7;
            const f32x4* p = (const f32x4*)(src + (size_t)g * 8);
            f32x4 v0 = p[0], v1 = p[1];
            ushort8 h, l;
            #pragma unroll
            for (int e = 0; e < 8; ++e) {
                float a = (e < 4) ? v0[e] : v1[e - 4];
                unsigned short hb = f2bf(a);
                h[e] = hb;
                l[e] = f2bf(a - bf2f(hb));
            }
            unsigned off = (unsigned)(row * 128 + kc * 16) ^ ((unsigned)(row & 7) << 4);
            *(ushort8*)((char*)hi + off) = h;
            *(ushort8*)((char*)lo + off) = l;
        }
    }
    __syncthreads();
    {
        const unsigned short* hi = (t < 128) ? sAhi : sBhi;
        const unsigned short* lo = (t < 128) ? sAlo : sBlo;
        int row = t & 127;
        float s = 0.f;
        #pragma unroll
        for (int kc = 0; kc < 8; ++kc) {
            unsigned off = (unsigned)(row * 128 + kc * 16) ^ ((unsigned)(row & 7) << 4);
            ushort8 h = *(const ushort8*)((const char*)hi + off);
            ushort8 l = *(const ushort8*)((const char*)lo + off);
            #pragma unroll
            for (int e = 0; e < 8; ++e) {
                float a = bf2f(h[e]) + bf2f(l[e]);
                s = fmaf(a, a, s);
            }
        }
        snrm[t] = s;
    }
    __syncthreads();

    const int lane = t & 63, w = t >> 6;
    const int wr = w >> 1, wc = w & 1;
    const int lr = lane & 15, kb = lane >> 4;

    f32x4 acc[4][4];
    #pragma unroll
    for (int a = 0; a < 4; ++a)
        #pragma unroll
        for (int b = 0; b < 4; ++b)
            acc[a][b] = (f32x4){0.f, 0.f, 0.f, 0.f};

    #pragma unroll
    for (int ks = 0; ks < 2; ++ks) {
        short8 bh[4], bl[4];
        #pragma unroll
        for (int fc = 0; fc < 4; ++fc) {
            int rowb = wc * 64 + fc * 16 + lr;
            unsigned off = (unsigned)(rowb * 128 + ks * 64 + kb * 16) ^ ((unsigned)(rowb & 7) << 4);
            bh[fc] = *(const short8*)((const char*)sBhi + off);
            bl[fc] = *(const short8*)((const char*)sBlo + off);
        }
        #pragma unroll
        for (int fr = 0; fr < 4; ++fr) {
            int rowa = wr * 64 + fr * 16 + lr;
            unsigned off = (unsigned)(rowa * 128 + ks * 64 + kb * 16) ^ ((unsigned)(rowa & 7) << 4);
            short8 ah = *(const short8*)((const char*)sAhi + off);
            short8 al = *(const short8*)((const char*)sAlo + off);
            #pragma unroll
            for (int fc = 0; fc < 4; ++fc) {
                acc[fr][fc] = __builtin_amdgcn_mfma_f32_16x16x32_bf16(ah, bh[fc], acc[fr][fc], 0, 0, 0);
                acc[fr][fc] = __builtin_amdgcn_mfma_f32_16x16x32_bf16(ah, bl[fc], acc[fr][fc], 0, 0, 0);
                acc[fr][fc] = __builtin_amdgcn_mfma_f32_16x16x32_bf16(al, bh[fc], acc[fr][fc], 0, 0, 0);
            }
        }
    }

    const int r4 = (lane >> 4) * 4;
    #pragma unroll
    for (int fr = 0; fr < 4; ++fr) {
        int rloc = wr * 64 + fr * 16 + r4;
        #pragma unroll
        for (int fc = 0; fc < 4; ++fc) {
            int cloc = wc * 64 + fc * 16 + lr;
            float n2v = snrm[128 + cloc];
            size_t gc = (size_t)(col0 + cloc);
            #pragma unroll
            for (int j = 0; j < 4; ++j) {
                float n1v = snrm[rloc + j];
                float d2  = n1v + n2v - 2.0f * acc[fr][fc][j];
                out[(size_t)(row0 + rloc + j) * (size_t)N2 + gc] = __expf(-d2);
            }
        }
    }
}

extern "C" void kernel_launch(void* const* d_in, const int* in_sizes, int n_in,
                              void* d_out, int out_size, void* d_ws, size_t ws_size,
                              hipStream_t stream) {
    const float* H1 = (const float*)d_in[0];
    const float* H2 = (const float*)d_in[1];
    float* out = (float*)d_out;
    const int n1 = in_sizes[0] / KD;   // 8192
    const int n2 = in_sizes[1] / KD;   // 8192

    if (ws_size >= WS_NEED) {
        gauss_prep<<<dim3(512), dim3(256), 0, stream>>>(H1, H2, (unsigned char*)d_ws);
        dim3 grid(n2 / 64, n1 / 64);
        gauss_main<<<grid, dim3(256), 0, stream>>>((const unsigned char*)d_ws, out, n2);
    } else {
        dim3 grid(n2 / 128, n1 / 128);
        gauss_fallback<<<grid, dim3(256), 0, stream>>>(H1, H2, out, n1, n2);
    }
}